// Round 1
// baseline (410.904 us; speedup 1.0000x reference)
//
#include <hip/hip_runtime.h>

// CTC batch cost (Keras ctc_batch_cost semantics), B=256, T=512, C=128, L=64.
// One 64-lane wave per batch element; 2 alpha states per lane + state 128
// replicated in all lanes (lane 63's value is the real one). One shfl_up per
// timestep. PF-deep register prefetch of the gathered probs hides HBM latency.

#define B_ 256
#define T_ 512
#define C_ 128
#define L_ 64
#define BLANK_ 127
#define NEGF (-1e30f)
#define EPSF (1e-7f)
#define PF 16

__device__ __forceinline__ float lse2(float a, float b) {
    // logaddexp, stable, finite for a=b=-1e30 (returns -1e30 + log 2)
    float m = fmaxf(a, b);
    float d = -fabsf(a - b);
    return m + __logf(1.0f + __expf(d));
}

__global__ __launch_bounds__(64) void ctc_fwd_kernel(
    const int* __restrict__ y_true, const float* __restrict__ y_pred,
    const int* __restrict__ input_len, const int* __restrict__ label_len,
    float* __restrict__ out)
{
    const int b = blockIdx.x;
    const int lane = threadIdx.x;          // 0..63
    const float* __restrict__ P = y_pred + (size_t)b * T_ * C_;

    // lane l owns states s=2l (blank) and s=2l+1 (label l)
    int label = y_true[b * L_ + lane];
    int label_prev = __shfl_up(label, 1);
    const bool skip = (lane > 0) && (label != BLANK_) && (label != label_prev);

    const int in_len = input_len[b];       // [B,1] flat
    const int lab    = label_len[b];
    const int tend = in_len < T_ ? in_len : T_;   // steps run for t in [1, tend)

    // t = 0 init: only s=0 and s=1 reachable
    float a0 = (lane == 0) ? __logf(P[BLANK_] + EPSF) : NEGF;
    float a1 = (lane == 0) ? __logf(P[label] + EPSF) : NEGF;
    float a2 = NEGF;                       // state 128 (valid in lane 63)

    // prefetch pipeline: raw probs for t = 1..PF
    float pb[PF], pl[PF];
#pragma unroll
    for (int k = 0; k < PF; ++k) {
        const int t = 1 + k;               // t <= PF << T
        pb[k] = P[t * C_ + BLANK_];
        pl[k] = P[t * C_ + label];
    }

    int t = 1;
    while (t < tend) {
#pragma unroll
        for (int k = 0; k < PF; ++k) {
            const int tc = t + k;
            if (tc >= tend) break;         // wave-uniform
            const float lpb = __logf(pb[k] + EPSF);
            const float lpl = __logf(pl[k] + EPSF);
            const int tn = tc + PF;        // prefetch PF steps ahead
            if (tn < tend) {
                pb[k] = P[tn * C_ + BLANK_];
                pl[k] = P[tn * C_ + label];
            }
            float p1 = __shfl_up(a1, 1);   // alpha[2l-1] from lane l-1
            if (lane == 0) p1 = NEGF;
            const float a0o = a0, a1o = a1;
            // state 2l (blank): s-1 = 2l-1 (p1); no skip
            a0 = lse2(a0o, p1) + lpb;
            // state 2l+1: s-1 = 2l (a0o), s-2 = 2l-1 (p1) if skip
            float tmp = lse2(a1o, a0o);
            tmp = skip ? lse2(tmp, p1) : tmp;
            a1 = tmp + lpl;
            // state 128: s-1 = 127 (a1o in lane 63); computed in all lanes,
            // only lane 63's is read (branch-free)
            a2 = lse2(a2, a1o) + lpb;
        }
        t += PF;
    }

    // loss = -logaddexp(alpha[2*lab], alpha[2*lab-1]);  lab in [32, 64]
    const float a_prev = __shfl(a1, lab - 1);            // state 2*lab-1
    const float a_last = (lab >= L_) ? __shfl(a2, 63)    // state 128
                                     : __shfl(a0, lab);  // state 2*lab
    if (lane == 0) out[b] = -lse2(a_last, a_prev);
}

extern "C" void kernel_launch(void* const* d_in, const int* in_sizes, int n_in,
                              void* d_out, int out_size, void* d_ws, size_t ws_size,
                              hipStream_t stream) {
    const int*   y_true    = (const int*)d_in[0];
    const float* y_pred    = (const float*)d_in[1];
    const int*   input_len = (const int*)d_in[2];
    const int*   label_len = (const int*)d_in[3];
    float* out = (float*)d_out;

    ctc_fwd_kernel<<<B_, 64, 0, stream>>>(y_true, y_pred, input_len, label_len, out);
}

// Round 2
// 149.708 us; speedup vs baseline: 2.7447x; 2.7447x over previous
//
#include <hip/hip_runtime.h>

// CTC batch cost (Keras ctc_batch_cost), B=256, T=512, C=128, L=64.
// One 64-lane wave per batch element (256 blocks ~ 1/CU). Probability rows are
// staged into LDS in 32-row chunks via global_load_lds (double-buffered,
// counted vmcnt so the next chunk's loads stay in flight during compute).
// Recurrence: lane l owns states 2l (blank) / 2l+1 (label l); state 128
// replicated, lane 63's is real. One shfl_up per timestep.

#define B_ 256
#define T_ 512
#define C_ 128
#define L_ 64
#define BLANK_ 127
#define NEGF (-1e30f)
#define EPSF (1e-7f)
#define CHUNK 32               // rows per staging chunk (16 KB/buffer)

__device__ __forceinline__ float lse2(float a, float b) {
    // logaddexp, stable, finite at a=b=-1e30
    float m = fmaxf(a, b);
    float d = -fabsf(a - b);
    return m + __logf(1.0f + __expf(d));
}

__device__ __forceinline__ void stage_chunk(const float* gsrc, float* ldst, int lane) {
    // 16 KB: 16 x (64 lanes x 16 B). LDS dest is wave-uniform base + lane*16.
#pragma unroll
    for (int i = 0; i < CHUNK / 2; ++i) {
        __builtin_amdgcn_global_load_lds(
            (const __attribute__((address_space(1))) void*)(gsrc + i * 256 + lane * 4),
            (__attribute__((address_space(3))) void*)(ldst + i * 256),
            16, 0, 0);
    }
}

__global__ __launch_bounds__(64) void ctc_fwd_kernel(
    const int* __restrict__ y_true, const float* __restrict__ y_pred,
    const int* __restrict__ input_len, const int* __restrict__ label_len,
    float* __restrict__ out)
{
    __shared__ float lds[2][CHUNK * C_];
    const int b = blockIdx.x;
    const int lane = threadIdx.x;          // 0..63
    const float* __restrict__ P = y_pred + (size_t)b * T_ * C_;

    // lane l owns states s=2l (blank) and s=2l+1 (label l)
    const int label = y_true[b * L_ + lane];
    const int label_prev = __shfl_up(label, 1);
    const bool skip = (lane > 0) && (label != label_prev);  // labels never == blank

    const int in_len = input_len[b];
    int lab = label_len[b];
    const int tend = in_len < T_ ? in_len : T_;
    const int nchunks = (tend + CHUNK - 1) / CHUNK;         // >= 8 here

    // force lab's load to retire NOW so it doesn't sit in the vmcnt queue
    asm volatile("" :: "v"(lab));

    stage_chunk(P, &lds[0][0], lane);
    if (nchunks > 1) stage_chunk(P + CHUNK * C_, &lds[1][0], lane);

    float a0 = NEGF, a1 = NEGF, a2 = NEGF;  // states 2l, 2l+1, 128

    for (int c = 0; c < nchunks; ++c) {
        // chunk c's 16 loads are the oldest; keep chunk c+1's 16 in flight
        if (c + 1 < nchunks) {
            asm volatile("s_waitcnt vmcnt(16)" ::: "memory");
        } else {
            asm volatile("s_waitcnt vmcnt(0)" ::: "memory");
        }
        const float* __restrict__ Lb = lds[c & 1];
        const int rem = tend - c * CHUNK;
        const int r_end = rem < CHUNK ? rem : CHUNK;
        int r = 0;
        if (c == 0) {
            // t = 0 init: only s=0 and s=1 reachable
            const float pb0 = Lb[BLANK_];
            const float pl0 = Lb[label];
            a0 = (lane == 0) ? __logf(pb0 + EPSF) : NEGF;
            a1 = (lane == 0) ? __logf(pl0 + EPSF) : NEGF;
            r = 1;
        }
#pragma unroll 4
        for (; r < r_end; ++r) {
            const float lpb = __logf(Lb[r * C_ + BLANK_] + EPSF);  // uniform -> broadcast
            const float lpl = __logf(Lb[r * C_ + label] + EPSF);   // per-lane gather
            float p1 = __shfl_up(a1, 1);     // alpha[2l-1] from lane l-1
            if (lane == 0) p1 = NEGF;
            const float a0o = a0, a1o = a1;
            a0 = lse2(a0o, p1) + lpb;                       // state 2l (blank)
            float tmp = lse2(a1o, a0o);                     // state 2l+1
            tmp = skip ? lse2(tmp, p1) : tmp;
            a1 = tmp + lpl;
            a2 = lse2(a2, a1o) + lpb;                       // state 128 (lane 63 real)
        }
        if (c + 2 < nchunks) stage_chunk(P + (size_t)(c + 2) * CHUNK * C_,
                                         &lds[c & 1][0], lane);
    }

    // loss = -logaddexp(alpha[2*lab], alpha[2*lab-1]), lab in [32, 64]
    const float a_prev = __shfl(a1, lab - 1);               // state 2*lab-1
    const float a_last = (lab >= L_) ? __shfl(a2, 63)       // state 128
                                     : __shfl(a0, lab);     // state 2*lab
    if (lane == 0) out[b] = -lse2(a_last, a_prev);
}

extern "C" void kernel_launch(void* const* d_in, const int* in_sizes, int n_in,
                              void* d_out, int out_size, void* d_ws, size_t ws_size,
                              hipStream_t stream) {
    const int*   y_true    = (const int*)d_in[0];
    const float* y_pred    = (const float*)d_in[1];
    const int*   input_len = (const int*)d_in[2];
    const int*   label_len = (const int*)d_in[3];
    float* out = (float*)d_out;

    ctc_fwd_kernel<<<B_, 64, 0, stream>>>(y_true, y_pred, input_len, label_len, out);
}

// Round 8
// 51.860 us; speedup vs baseline: 7.9233x; 2.8868x over previous
//
#include <hip/hip_runtime.h>

// CTC batch cost (Keras ctc_batch_cost), B=256, T=512, C=128, L=64.
// One 64-lane wave per batch element. Chain-latency-optimized recurrence:
//  - DPP wave_shr:1 for the lane-shift (no DS op on the chain)
//  - per-16-step phase split: gather+log2 label probs into regs (ILP), then
//    pure-register recurrence
//  - blank-col log-probs distributed via v_readlane (uniform, off-chain)
//  - log2 domain throughout (v_exp_f32/v_log_f32 are base-2); convert at end
//  - state-128 recurrence only when label_length==64 (uniform template)
// Staging: 32-row chunks via global_load_lds, double-buffered, counted vmcnt.

#define B_ 256
#define T_ 512
#define C_ 128
#define L_ 64
#define BLANK_ 127
#define NEGF (-1e30f)
#define EPSF (1e-7f)
#define CHUNK 32
#define LN2F 0.6931471805599453f

#define EXP2(x) __builtin_amdgcn_exp2f(x)   // v_exp_f32 (base-2)
#define LOG2(x) __builtin_amdgcn_logf(x)    // v_log_f32 (base-2)

__device__ __forceinline__ float lse2_2(float a, float b) {
    // log2-domain logaddexp; finite at a=b=NEGF
    float m = fmaxf(a, b);
    float d = fminf(a, b) - m;
    return m + LOG2(1.0f + EXP2(d));
}

__device__ __forceinline__ float lse3_2(float a, float b, float c) {
    float m = fmaxf(fmaxf(a, b), c);   // v_max3
    float s = EXP2(a - m) + EXP2(b - m) + EXP2(c - m);
    return m + LOG2(s);
}

__device__ __forceinline__ float dpp_shr1(float x, float old) {
    // lane i <- lane i-1; lane 0 <- old   (DPP wave_shr:1 = 0x138)
    return __int_as_float(__builtin_amdgcn_update_dpp(
        __float_as_int(old), __float_as_int(x), 0x138, 0xf, 0xf, false));
}

__device__ __forceinline__ void stage_chunk(const float* gsrc, float* ldst, int lane) {
    // 16 KB: 16 x (64 lanes x 16 B); LDS dest = wave-uniform base + lane*16
#pragma unroll
    for (int i = 0; i < CHUNK / 2; ++i) {
        __builtin_amdgcn_global_load_lds(
            (const __attribute__((address_space(1))) void*)(gsrc + i * 256 + lane * 4),
            (__attribute__((address_space(3))) void*)(ldst + i * 256),
            16, 0, 0);
    }
}

template<bool HAS128, bool FULL>
__device__ __forceinline__ void group16(const float* __restrict__ Lb, int base,
                                        int label, bool skip, float lpbv,
                                        int lo, int hi,   // valid row bounds (!FULL)
                                        float& a0, float& a1, float& a2)
{
    // Phase A: gather label probs for 16 rows, then log2 — full ILP, off-chain
    float lpl[16];
#pragma unroll
    for (int u = 0; u < 16; ++u)
        lpl[u] = Lb[(base + u) * C_ + label];
#pragma unroll
    for (int u = 0; u < 16; ++u)
        lpl[u] = LOG2(lpl[u] + EPSF);

    // Phase B: pure-register recurrence
#pragma unroll
    for (int u = 0; u < 16; ++u) {
        const int r = base + u;
        const float lpb = __int_as_float(
            __builtin_amdgcn_readlane(__float_as_int(lpbv), r));  // uniform
        float p1 = dpp_shr1(a1, NEGF);        // alpha[2l-1] from lane l-1
        float p1m = skip ? p1 : NEGF;
        const float a0o = a0, a1o = a1;
        const float na0 = lse2_2(a0o, p1) + lpb;            // state 2l (blank)
        const float na1 = lse3_2(a1o, a0o, p1m) + lpl[u];   // state 2l+1
        if (FULL) {
            a0 = na0; a1 = na1;
            if (HAS128) a2 = lse2_2(a2, a1o) + lpb;         // state 128
        } else {
            const bool v = (r >= lo) & (r < hi);            // uniform
            const float na2 = HAS128 ? (lse2_2(a2, a1o) + lpb) : a2;
            a0 = v ? na0 : a0o;
            a1 = v ? na1 : a1o;
            if (HAS128) a2 = v ? na2 : a2;
        }
    }
}

template<bool HAS128>
__device__ __forceinline__ void run(const float* __restrict__ P,
                                    float (*lds)[CHUNK * C_],
                                    int label, bool skip, int tend, int lane,
                                    float& a0, float& a1, float& a2)
{
    const int nchunks = (tend + CHUNK - 1) / CHUNK;   // >= 8 (tend >= 256)
    stage_chunk(P, lds[0], lane);
    stage_chunk(P + CHUNK * C_, lds[1], lane);

    for (int c = 0; c < nchunks; ++c) {
        if (c + 1 < nchunks) asm volatile("s_waitcnt vmcnt(16)" ::: "memory");
        else                 asm volatile("s_waitcnt vmcnt(0)" ::: "memory");
        const float* __restrict__ Lb = lds[c & 1];

        // blank column for this chunk: lanes 0..31 hold rows 0..31
        const float pbv  = Lb[(lane & 31) * C_ + BLANK_];
        const float lpbv = LOG2(pbv + EPSF);

        if (c == 0) {
            // t = 0 init: only s=0 and s=1 reachable
            const float pb0 = Lb[BLANK_];
            const float pl0 = Lb[label];
            a0 = (lane == 0) ? LOG2(pb0 + EPSF) : NEGF;
            a1 = (lane == 0) ? LOG2(pl0 + EPSF) : NEGF;
            group16<HAS128, false>(Lb, 0,  label, skip, lpbv, 1, 16, a0, a1, a2);
            group16<HAS128, true >(Lb, 16, label, skip, lpbv, 0, 0,  a0, a1, a2);
        } else {
            const int rem = tend - c * CHUNK;
            if (rem >= CHUNK) {
                group16<HAS128, true>(Lb, 0,  label, skip, lpbv, 0, 0, a0, a1, a2);
                group16<HAS128, true>(Lb, 16, label, skip, lpbv, 0, 0, a0, a1, a2);
            } else if (rem > 16) {
                group16<HAS128, true >(Lb, 0,  label, skip, lpbv, 0, 0,   a0, a1, a2);
                group16<HAS128, false>(Lb, 16, label, skip, lpbv, 0, rem, a0, a1, a2);
            } else {
                group16<HAS128, false>(Lb, 0,  label, skip, lpbv, 0, rem, a0, a1, a2);
            }
        }
        if (c + 2 < nchunks)
            stage_chunk(P + (size_t)(c + 2) * CHUNK * C_, lds[c & 1], lane);
    }
}

__global__ __launch_bounds__(64) void ctc_fwd_kernel(
    const int* __restrict__ y_true, const float* __restrict__ y_pred,
    const int* __restrict__ input_len, const int* __restrict__ label_len,
    float* __restrict__ out)
{
    __shared__ float lds[2][CHUNK * C_];
    const int b = blockIdx.x;
    const int lane = threadIdx.x;
    const float* __restrict__ P = y_pred + (size_t)b * T_ * C_;

    const int label = y_true[b * L_ + lane];
    const int label_prev = __shfl_up(label, 1);
    const bool skip = (lane > 0) && (label != label_prev);

    const int in_len = input_len[b];
    const int lab    = label_len[b];
    const int tend = in_len < T_ ? in_len : T_;

    float a0 = NEGF, a1 = NEGF, a2 = NEGF;
    if (lab == L_) run<true >(P, lds, label, skip, tend, lane, a0, a1, a2);
    else           run<false>(P, lds, label, skip, tend, lane, a0, a1, a2);

    // loss = -ln2 * lse2_log2(alpha[2*lab], alpha[2*lab-1])
    const float a_prev = __shfl(a1, lab - 1);            // state 2*lab-1
    const float a_last = (lab >= L_) ? __shfl(a2, 63)    // state 128
                                     : __shfl(a0, lab);  // state 2*lab
    if (lane == 0) out[b] = -LN2F * lse2_2(a_last, a_prev);
}

extern "C" void kernel_launch(void* const* d_in, const int* in_sizes, int n_in,
                              void* d_out, int out_size, void* d_ws, size_t ws_size,
                              hipStream_t stream) {
    const int*   y_true    = (const int*)d_in[0];
    const float* y_pred    = (const float*)d_in[1];
    const int*   input_len = (const int*)d_in[2];
    const int*   label_len = (const int*)d_in[3];
    float* out = (float*)d_out;

    ctc_fwd_kernel<<<B_, 64, 0, stream>>>(y_true, y_pred, input_len, label_len, out);
}

// Round 9
// 30.374 us; speedup vs baseline: 13.5280x; 1.7074x over previous
//
#include <hip/hip_runtime.h>

// CTC batch cost (Keras ctc_batch_cost), B=256, T=512, C=128, L=64.
// One 64-lane wave per batch element. Linear-domain recurrence with per-lane
// power-of-2 exponent tracking (zero transcendentals on the chain):
//   A0' = (A0 + P1)*pb ; A1' = (A1 + (skip ? A0+P1 : A0))*pl ; A2' = (A2+A1)*pb
// P1 = DPP wave_shr:1 of neighbor A1, aligned by 2^(e_prev - e) (exact).
// Per-lane renorm every 4 steps: e += exponent(max states), scale by 2^-e.
// First 128 steps: "fat" variant with per-step dead-lane exponent adoption
// (state s live only at t >= ceil(s/2)); after t=128 all lanes live -> "lean"
// variant reuses a per-window constant alignment scale.
// Staging: 32-row chunks via global_load_lds, double-buffered, counted vmcnt.

#define B_ 256
#define T_ 512
#define C_ 128
#define L_ 64
#define BLANK_ 127
#define EPSF (1e-7f)
#define CHUNK 32
#define LN2F 0.6931471805599453f

#define EXP2(x) __builtin_amdgcn_exp2f(x)   // v_exp_f32 (base-2)
#define LOG2(x) __builtin_amdgcn_logf(x)    // v_log_f32 (base-2)

__device__ __forceinline__ float lse2_2(float a, float b) {
    // log2-domain logaddexp (used once, at the end)
    float m = fmaxf(a, b);
    float d = fminf(a, b) - m;
    return m + LOG2(1.0f + EXP2(d));
}

__device__ __forceinline__ float dppf(float x) {
    // lane i <- lane i-1; lane 0 <- 0
    return __int_as_float(__builtin_amdgcn_update_dpp(
        0, __float_as_int(x), 0x138, 0xf, 0xf, false));
}
__device__ __forceinline__ int dppi(int x) {
    return __builtin_amdgcn_update_dpp(0, x, 0x138, 0xf, 0xf, false);
}

__device__ __forceinline__ float delta_scale(int ep, int e) {
    // 2^clamp(ep-e, -126, 126) as exact float bits
    int d = ep - e;
    d = d < -126 ? -126 : d;
    d = d > 126 ? 126 : d;
    return __int_as_float((d + 127) << 23);
}

template<bool HAS128>
__device__ __forceinline__ void renorm(float& A0, float& A1, float& A2, int& e) {
    float m = fmaxf(A0, A1);
    if (HAS128) m = fmaxf(m, A2);
    const int mb = __float_as_int(m);
    // valid iff m is normal and finite: 0x00800000 <= mb < 0x7f800000
    const bool valid = (unsigned)(mb - 0x00800000) < 0x7f000000u;
    int ex = (mb >> 23) - 127;
    ex = valid ? ex : 0;
    const float s = __int_as_float((127 - ex) << 23);   // exact 2^-ex
    A0 *= s; A1 *= s;
    if (HAS128) A2 *= s;
    e += ex;
}

__device__ __forceinline__ void stage_chunk(const float* gsrc, float* ldst, int lane) {
    // 16 KB: 16 x (64 lanes x 16 B); LDS dest = wave-uniform base + lane*16
#pragma unroll
    for (int i = 0; i < CHUNK / 2; ++i) {
        __builtin_amdgcn_global_load_lds(
            (const __attribute__((address_space(1))) void*)(gsrc + i * 256 + lane * 4),
            (__attribute__((address_space(3))) void*)(ldst + i * 256),
            16, 0, 0);
    }
}

// -------- fat step group: per-step exponent adoption for dead lanes --------
template<bool HAS128, bool FULL>
__device__ __forceinline__ void group16_fat(const float* __restrict__ Lb, int base,
    int label, bool skip, float pbv, int lo, int hi,
    float& A0, float& A1, float& A2, int& e)
{
    float pl[16];
#pragma unroll
    for (int u = 0; u < 16; ++u) pl[u] = Lb[(base + u) * C_ + label];
#pragma unroll
    for (int u = 0; u < 16; ++u) pl[u] += EPSF;

#pragma unroll
    for (int u = 0; u < 16; ++u) {
        const int r = base + u;
        const float pb = __int_as_float(
            __builtin_amdgcn_readlane(__float_as_int(pbv), r));
        const float p1 = dppf(A1);
        const int   ep = dppi(e);
        const bool dead = (fmaxf(A0, A1) == 0.0f);
        const int e1 = dead ? ep : e;            // adopt neighbor exp if dead
        const float sc = delta_scale(ep, e1);
        const float P1 = p1 * sc;
        const float A0o = A0, A1o = A1;
        const float X   = A0o + P1;
        const float nA0 = X * pb;
        const float Y   = skip ? X : A0o;
        const float nA1 = (A1o + Y) * pl[u];
        const float nA2 = HAS128 ? (A2 + A1o) * pb : A2;
        if (FULL) {
            A0 = nA0; A1 = nA1; e = e1;
            if (HAS128) A2 = nA2;
        } else {
            const bool v = (r >= lo) & (r < hi);  // wave-uniform
            A0 = v ? nA0 : A0o;
            A1 = v ? nA1 : A1o;
            e  = v ? e1  : e;
            if (HAS128) A2 = v ? nA2 : A2;
        }
        if ((u & 3) == 3) renorm<HAS128>(A0, A1, A2, e);
    }
}

// -------- lean step group: all lanes live; alignment scale per 4-window --------
template<bool HAS128, bool FULL>
__device__ __forceinline__ void group16_lean(const float* __restrict__ Lb, int base,
    int label, bool skip, float pbv, int lo, int hi,
    float& A0, float& A1, float& A2, int& e, float& sc)
{
    float pl[16];
#pragma unroll
    for (int u = 0; u < 16; ++u) pl[u] = Lb[(base + u) * C_ + label];
#pragma unroll
    for (int u = 0; u < 16; ++u) pl[u] += EPSF;

#pragma unroll
    for (int u = 0; u < 16; ++u) {
        const int r = base + u;
        const float pb = __int_as_float(
            __builtin_amdgcn_readlane(__float_as_int(pbv), r));
        const float P1 = dppf(A1) * sc;
        const float A0o = A0, A1o = A1;
        const float X   = A0o + P1;
        const float nA0 = X * pb;
        const float Y   = skip ? X : A0o;
        const float nA1 = (A1o + Y) * pl[u];
        const float nA2 = HAS128 ? (A2 + A1o) * pb : A2;
        if (FULL) {
            A0 = nA0; A1 = nA1;
            if (HAS128) A2 = nA2;
        } else {
            const bool v = (r >= lo) & (r < hi);
            A0 = v ? nA0 : A0o;
            A1 = v ? nA1 : A1o;
            if (HAS128) A2 = v ? nA2 : A2;
        }
        if ((u & 3) == 3) {                      // e changes only here
            renorm<HAS128>(A0, A1, A2, e);
            sc = delta_scale(dppi(e), e);
        }
    }
}

template<bool HAS128>
__device__ __forceinline__ void run(const float* __restrict__ P,
                                    float (*lds)[CHUNK * C_],
                                    int label, bool skip, int tend, int lane,
                                    float& A0, float& A1, float& A2, int& e)
{
    const int nchunks = (tend + CHUNK - 1) / CHUNK;   // >= 8 (tend >= 256)
    stage_chunk(P, lds[0], lane);
    stage_chunk(P + CHUNK * C_, lds[1], lane);
    float sc = 1.0f;

    for (int c = 0; c < nchunks; ++c) {
        if (c + 1 < nchunks) asm volatile("s_waitcnt vmcnt(16)" ::: "memory");
        else                 asm volatile("s_waitcnt vmcnt(0)" ::: "memory");
        const float* __restrict__ Lb = lds[c & 1];

        // blank column (+eps) for this chunk: lanes 0..31 hold rows 0..31
        const float pbv = Lb[(lane & 31) * C_ + BLANK_] + EPSF;

        if (c == 0) {
            // t=0 init: only s=0 and s=1 reachable
            A0 = (lane == 0) ? Lb[BLANK_] + EPSF : 0.0f;
            A1 = (lane == 0) ? Lb[label]  + EPSF : 0.0f;
            group16_fat<HAS128, false>(Lb, 0,  label, skip, pbv, 1, 16, A0, A1, A2, e);
            group16_fat<HAS128, true >(Lb, 16, label, skip, pbv, 0, 0,  A0, A1, A2, e);
        } else if (c < 4) {                       // t < 128: dead lanes possible
            group16_fat<HAS128, true>(Lb, 0,  label, skip, pbv, 0, 0, A0, A1, A2, e);
            group16_fat<HAS128, true>(Lb, 16, label, skip, pbv, 0, 0, A0, A1, A2, e);
        } else {                                  // t >= 128: all lanes live
            if (c == 4) sc = delta_scale(dppi(e), e);
            const int rem = tend - c * CHUNK;
            if (rem >= CHUNK) {
                group16_lean<HAS128, true>(Lb, 0,  label, skip, pbv, 0, 0, A0, A1, A2, e, sc);
                group16_lean<HAS128, true>(Lb, 16, label, skip, pbv, 0, 0, A0, A1, A2, e, sc);
            } else if (rem > 16) {
                group16_lean<HAS128, true >(Lb, 0,  label, skip, pbv, 0, 0,   A0, A1, A2, e, sc);
                group16_lean<HAS128, false>(Lb, 16, label, skip, pbv, 0, rem, A0, A1, A2, e, sc);
            } else {
                group16_lean<HAS128, false>(Lb, 0,  label, skip, pbv, 0, rem, A0, A1, A2, e, sc);
            }
        }
        if (c + 2 < nchunks)
            stage_chunk(P + (size_t)(c + 2) * CHUNK * C_, lds[c & 1], lane);
    }
}

__global__ __launch_bounds__(64) void ctc_fwd_kernel(
    const int* __restrict__ y_true, const float* __restrict__ y_pred,
    const int* __restrict__ input_len, const int* __restrict__ label_len,
    float* __restrict__ out)
{
    __shared__ float lds[2][CHUNK * C_];
    const int b = blockIdx.x;
    const int lane = threadIdx.x;
    const float* __restrict__ P = y_pred + (size_t)b * T_ * C_;

    const int label = y_true[b * L_ + lane];
    const int label_prev = __shfl_up(label, 1);
    const bool skip = (lane > 0) && (label != label_prev);

    const int in_len = input_len[b];
    const int lab    = label_len[b];
    const int tend = in_len < T_ ? in_len : T_;

    float A0 = 0.0f, A1 = 0.0f, A2 = 0.0f;   // states 2l, 2l+1, 128 (linear)
    int e = 0;                               // per-lane power-of-2 exponent
    if (lab == L_) run<true >(P, lds, label, skip, tend, lane, A0, A1, A2, e);
    else           run<false>(P, lds, label, skip, tend, lane, A0, A1, A2, e);

    // back to log2 once; loss = -ln2 * logaddexp2(alpha[2lab], alpha[2lab-1])
    const float ef = (float)e;
    const float l0 = LOG2(A0) + ef;
    const float l1 = LOG2(A1) + ef;
    const float a_prev = __shfl(l1, lab - 1);            // state 2*lab-1
    float a_last;
    if (lab >= L_) {
        const float l2 = LOG2(A2) + ef;
        a_last = __shfl(l2, 63);                         // state 128
    } else {
        a_last = __shfl(l0, lab);                        // state 2*lab
    }
    if (lane == 0) out[b] = -LN2F * lse2_2(a_last, a_prev);
}

extern "C" void kernel_launch(void* const* d_in, const int* in_sizes, int n_in,
                              void* d_out, int out_size, void* d_ws, size_t ws_size,
                              hipStream_t stream) {
    const int*   y_true    = (const int*)d_in[0];
    const float* y_pred    = (const float*)d_in[1];
    const int*   input_len = (const int*)d_in[2];
    const int*   label_len = (const int*)d_in[3];
    float* out = (float*)d_out;

    ctc_fwd_kernel<<<B_, 64, 0, stream>>>(y_true, y_pred, input_len, label_len, out);
}